// Round 1
// 447.799 us; speedup vs baseline: 1.0354x; 1.0354x over previous
//
#include <hip/hip_runtime.h>

// out[b,t,u] = h0[b,u] + 0.5f * cumsum_t(x[b,:,u])
// x: (16, 4096, 1024) fp32, h0: (16, 1024) fp32, out: (16, 4096, 1024) fp32.
//
// Parallel two-level scan along T instead of one serial thread per chain:
//   - block = 512 threads = 8 float4 u-columns x 64 T-segments (one b, 32 u)
//   - chunk = 256 t-steps; each thread owns 4 consecutive rows (4x float4 in
//     registers -> x is read exactly ONCE, no re-read pass)
//   - per chunk: segment sums -> shfl_up scan over 8 s-locals in-wave ->
//     cross-wave combine via 1KiB LDS -> fused output write with carry.
// Grid = 512 blocks x 8 waves = 4096 waves = 16 waves/CU (vs 1 wave/CU
// before). Raw s_barrier + lgkmcnt(0) only (no vmcnt drain), so the next
// chunk's prefetched loads stay in flight across the barrier.

#define B_DIM 16
#define T_DIM 4096
#define U_DIM 1024
#define U4 256                 // float4 columns per row
#define BLOCK 512
#define NWAVE 8
#define U4B 8                  // float4 columns per block (32 floats of u)
#define LPC 4                  // t-rows per thread per chunk
#define CCHUNK 256             // 64 segments * 4 rows
#define NCHUNK (T_DIM / CCHUNK)  // 16

typedef float f4 __attribute__((ext_vector_type(4)));

__device__ __forceinline__ f4 shfl_up4(f4 v, int delta) {
  f4 r;
  r.x = __shfl_up(v.x, delta, 64);
  r.y = __shfl_up(v.y, delta, 64);
  r.z = __shfl_up(v.z, delta, 64);
  r.w = __shfl_up(v.w, delta, 64);
  return r;
}

__global__ __launch_bounds__(BLOCK, 4) void rac_scan_kernel(
    const float* __restrict__ x,
    const float* __restrict__ h0,
    float* __restrict__ out) {
  const int tid = threadIdx.x;
  const int u4l = tid & (U4B - 1);   // 0..7  : float4 column within block
  const int s   = tid >> 3;          // 0..63 : T-segment index
  const int w   = tid >> 6;          // 0..7  : wave index
  const int sl  = s & 7;             // segment index within wave

  const int b  = blockIdx.x >> 5;    // 16 batches
  const int ug = blockIdx.x & 31;    // 32 u-groups of 32 floats
  const int u4 = ug * U4B + u4l;

  const f4* xp = (const f4*)x + (size_t)b * T_DIM * U4 + u4;
  f4* op       = (f4*)out      + (size_t)b * T_DIM * U4 + u4;
  const f4 h0v = ((const f4*)h0)[b * U4 + u4];

  __shared__ f4 lds[2][NWAVE][U4B];  // double-buffered wave totals (2 KiB)

  f4 carry = 0.0f;                   // running chain sum over previous chunks
  f4 va[LPC], vb[LPC];

#define LOADC(buf, k)                                                      \
  _Pragma("unroll") for (int i = 0; i < LPC; ++i) {                        \
    (buf)[i] = __builtin_nontemporal_load(                                 \
        xp + (size_t)((k) * CCHUNK + s * LPC + i) * U4);                   \
  }

  LOADC(va, 0)

  for (int k = 0; k < NCHUNK; ++k) {
    // Prefetch next chunk before doing any math on this one.
    if (k + 1 < NCHUNK) {
      LOADC(vb, k + 1)
    }

    // Segment sum (componentwise over 4 u-columns).
    f4 seg  = (va[0] + va[1]) + (va[2] + va[3]);

    // Inclusive scan over the 8 segments resident in this wave.
    f4 incl = seg;
#pragma unroll
    for (int d = 1; d < 8; d <<= 1) {
      f4 t = shfl_up4(incl, 8 * d);
      if (sl >= d) incl += t;
    }

    // Cross-wave combine: wave-inclusive totals through LDS.
    if (sl == 7) lds[k & 1][w][u4l] = incl;
    asm volatile("s_waitcnt lgkmcnt(0)" ::: "memory");  // ds_write visible
    __builtin_amdgcn_s_barrier();                        // no vmcnt drain!
    asm volatile("" ::: "memory");

    f4 prev  = 0.0f;  // sum of waves before mine
    f4 total = 0.0f;  // whole-chunk sum
#pragma unroll
    for (int wp = 0; wp < NWAVE; ++wp) {
      f4 v = lds[k & 1][wp][u4l];
      total += v;
      if (wp < w) prev += v;
    }

    // Exclusive prefix for this thread's first row, then stream 4 outputs.
    f4 run = carry + prev + (incl - seg);
#pragma unroll
    for (int i = 0; i < LPC; ++i) {
      run += va[i];
      f4 o = h0v + 0.5f * run;
      __builtin_nontemporal_store(
          o, op + (size_t)(k * CCHUNK + s * LPC + i) * U4);
    }

    carry += total;

#pragma unroll
    for (int i = 0; i < LPC; ++i) va[i] = vb[i];
  }
#undef LOADC
}

extern "C" void kernel_launch(void* const* d_in, const int* in_sizes, int n_in,
                              void* d_out, int out_size, void* d_ws,
                              size_t ws_size, hipStream_t stream) {
  const float* x  = (const float*)d_in[0];
  const float* h0 = (const float*)d_in[1];
  float* out      = (float*)d_out;

  dim3 grid(B_DIM * 32);  // 512 blocks: 16 b x 32 u-groups
  dim3 block(BLOCK);      // 512 threads = 8 waves
  rac_scan_kernel<<<grid, block, 0, stream>>>(x, h0, out);
}